// Round 8
// baseline (235.333 us; speedup 1.0000x reference)
//
#include <hip/hip_runtime.h>
#include <hip/hip_fp16.h>
#include <stdint.h>
#include <math.h>

// ---------------------------------------------------------------------------
// DFT_12223476924859: STFT via batched real-pair FFT (memory-bound).
//   out0[b,k,t] = Re X_t[k], out1[b,k,t] = Im X_t[k],  X_t = FFT(win*frame_t)
// Two real frames packed per complex 2048-pt FFT.
//
// R8 = R7 resubmit (R7 bench was an infra failure: container acquisition
// failed twice; kernel never ran). One cosmetic cleanup: transpose_out's
// 8B sc read via plain float2 (alignment proved: KS/k0/klp all even).
//
// R7: VGPR-cap fix + small traffic polish.
//  - fft_pairs __launch_bounds__(256,5) -> (256,4). (256,5) capped the
//    allocator at ~102 VGPR; the radix-8 butterfly (8 float2 data + 7
//    twiddle powers + 8 window taps + addrs) exceeds that -> scratch
//    spills serialized every phase. Cap 128 removes them; R4 showed the
//    5th block/CU is worthless anyway.
//  - transpose_out: sc reads vectorized to 8 B/lane (2 adjacent k).
//  - out writes via __builtin_nontemporal_store (write-once stream;
//    don't evict the L3 lines holding sc between the two kernels).
// R6: fp16 scratch (-31.9us; fills contend for HBM, bytes pay ~double).
// R5: radix-8 Stockham 8*8*8*4, 5 phases / 4 barriers; final radix-4
//   twiddle-free; 3 sincos/thread (window via cos(theta+m*pi/4) ids).
// R4: XW(w)=w^((w>>4)&15) involution swizzle (bank-floor verified), 32 KB
//   LDS ping-pong, frame-B global-load aliasing (B taps 0..5 = A 2..7).
// R3: sincos twiddles (no tables), fused load+window+stage-1.
// Harness fills (~79us, 538 MB re-poison @ ~6.9 TB/s) are outside our
// control and share HBM with our kernels.
// ---------------------------------------------------------------------------

#define N_FFT   2048
#define HOP     512
#define BATCH   16
#define LENGTH  262144
#define FRAMES  513
#define OHALF   ((size_t)BATCH * N_FFT * FRAMES)  // 16,809,984
#define KS      1026                      // per-frame half2 stride in scratch
#define PAIRS   257                       // ceil(513/2)

// XOR bank swizzle (float2 units): involution, zero memory overhead.
#define XW(w) ((w) ^ (((w) >> 4) & 15))

#define TWO_PI_OVER_N  3.0679615757712823e-3f   // 2*pi/2048
#define RSQRT2         0.70710678118654752f     // sqrt(2)/2

__device__ __forceinline__ float2 cmul(float2 a, float2 w) {
    return make_float2(a.x * w.x - a.y * w.y, a.x * w.y + a.y * w.x);
}
__device__ __forceinline__ float2 csq(float2 w) {
    return make_float2(w.x * w.x - w.y * w.y, 2.f * w.x * w.y);
}

// DFT4 with omega_4 = -i:  y1 = t1 - j t3, y3 = t1 + j t3.
__device__ __forceinline__ void dft4(float2 z0, float2 z1, float2 z2, float2 z3,
                                     float2& y0, float2& y1, float2& y2, float2& y3)
{
    float2 t0 = make_float2(z0.x + z2.x, z0.y + z2.y);
    float2 t1 = make_float2(z0.x - z2.x, z0.y - z2.y);
    float2 t2 = make_float2(z1.x + z3.x, z1.y + z3.y);
    float2 t3 = make_float2(z1.x - z3.x, z1.y - z3.y);
    y0 = make_float2(t0.x + t2.x, t0.y + t2.y);
    y1 = make_float2(t1.x + t3.y, t1.y - t3.x);
    y2 = make_float2(t0.x - t2.x, t0.y - t2.y);
    y3 = make_float2(t1.x - t3.y, t1.y + t3.x);
}

// Radix-8 DIF butterfly on a[0..7], then Y[XW(obase + m*s)] = y_m * w1^m.
// y_{2m} = DFT4(a_n + a_{n+4})_m ; y_{2m+1} = DFT4((a_n - a_{n+4}) w8^n)_m.
__device__ __forceinline__ void r8_store(float2* __restrict__ Y, const float2 a[8],
                                         float2 w1, int obase, int s)
{
    float2 u0 = make_float2(a[0].x + a[4].x, a[0].y + a[4].y);
    float2 u1 = make_float2(a[1].x + a[5].x, a[1].y + a[5].y);
    float2 u2 = make_float2(a[2].x + a[6].x, a[2].y + a[6].y);
    float2 u3 = make_float2(a[3].x + a[7].x, a[3].y + a[7].y);
    float2 v0 = make_float2(a[0].x - a[4].x, a[0].y - a[4].y);
    float2 v1 = make_float2(a[1].x - a[5].x, a[1].y - a[5].y);
    float2 v2 = make_float2(a[2].x - a[6].x, a[2].y - a[6].y);
    float2 v3 = make_float2(a[3].x - a[7].x, a[3].y - a[7].y);
    // v_n *= w8^n: w8 = (c,-c), w8^2 = -i, w8^3 = (-c,-c), c = sqrt(2)/2
    v1 = make_float2(RSQRT2 * (v1.x + v1.y), RSQRT2 * (v1.y - v1.x));
    v2 = make_float2(v2.y, -v2.x);
    v3 = make_float2(RSQRT2 * (v3.y - v3.x), -RSQRT2 * (v3.x + v3.y));

    float2 E0, E1, E2, E3, O0, O1, O2, O3;
    dft4(u0, u1, u2, u3, E0, E1, E2, E3);
    dft4(v0, v1, v2, v3, O0, O1, O2, O3);

    float2 w2 = csq(w1);
    float2 w3 = cmul(w1, w2);
    float2 w4 = csq(w2);
    float2 w5 = cmul(w2, w3);
    float2 w6 = csq(w3);
    float2 w7 = cmul(w3, w4);

    Y[XW(obase)]         = E0;
    Y[XW(obase + s)]     = cmul(O0, w1);
    Y[XW(obase + 2 * s)] = cmul(E1, w2);
    Y[XW(obase + 3 * s)] = cmul(O1, w3);
    Y[XW(obase + 4 * s)] = cmul(E2, w4);
    Y[XW(obase + 5 * s)] = cmul(O2, w5);
    Y[XW(obase + 6 * s)] = cmul(E3, w6);
    Y[XW(obase + 7 * s)] = cmul(O3, w7);
}

// Middle radix-8 stage (S = 8 or 64): read, twiddle from 1 sincos, write.
template<int S>
__device__ __forceinline__ void r8_stage(const float2* __restrict__ X,
                                         float2* __restrict__ Y, int idx)
{
    float2 a[8];
    const int wi = XW(idx);               // XW(idx+256m) = XW(idx)+256m
    #pragma unroll
    for (int m = 0; m < 8; ++m) a[m] = X[wi + 256 * m];
    const int sp = idx & ~(S - 1);
    float sn, cs;
    __sincosf((float)sp * TWO_PI_OVER_N, &sn, &cs);
    r8_store(Y, a, make_float2(cs, -sn), idx + 7 * sp, S);
}

// ============================ FFT path =====================================

// One block = one pair of frames (2p, 2p+1) of one batch.
// z = wxA + i*wxB; radix-8 Stockham (8*8*8*4), XOR-swizzled LDS ping-pong.
__global__ __launch_bounds__(256, 4) void fft_pairs(
    const float* __restrict__ x, __half2* __restrict__ sc)
{
    __shared__ float2 buf[2][2048];   // exactly 32 KB ping-pong

    const int tid = threadIdx.x;      // = butterfly idx for radix-8 stages
    const int p   = blockIdx.x;       // pair index 0..256
    const int b   = blockIdx.y;
    const int fA  = 2 * p;
    const int fB  = 2 * p + 1;
    const bool hasB = (fB < FRAMES);
    const float* xb = x + (size_t)b * LENGTH;
    const bool interior = (p >= 1 && p <= 254);

    // ---- phase 0: load + window + radix-8 stage s=1 (fused) ----
    // tap n = tid + 256m; win(n) = 0.5 - 0.5 cos(theta + m*pi/4),
    // theta = 2*pi*tid/2048; stage twiddle w1 = (cos theta, -sin theta).
    {
        const int baseA = fA * HOP - (N_FFT / 2);
        float xa[8], xv[8];
        if (interior) {
            #pragma unroll
            for (int m = 0; m < 8; ++m) xa[m] = xb[baseA + tid + 256 * m];
            #pragma unroll
            for (int m = 0; m < 6; ++m) xv[m] = xa[m + 2];   // baseB = baseA+512
            xv[6] = xb[baseA + 512 + tid + 256 * 6];
            xv[7] = xb[baseA + 512 + tid + 256 * 7];
        } else {
            const int baseB = baseA + 512;
            #pragma unroll
            for (int m = 0; m < 8; ++m) {
                int ja = baseA + tid + 256 * m;
                ja = (ja < 0) ? -ja : ((ja >= LENGTH) ? 2 * LENGTH - 2 - ja : ja);
                xa[m] = xb[ja];
                float vb = 0.f;
                if (hasB) {
                    int jb = baseB + tid + 256 * m;
                    jb = (jb < 0) ? -jb : ((jb >= LENGTH) ? 2 * LENGTH - 2 - jb : jb);
                    vb = xb[jb];
                }
                xv[m] = vb;
            }
        }
        float sn, cs;
        __sincosf((float)tid * TWO_PI_OVER_N, &sn, &cs);
        const float cd = RSQRT2 * (cs - sn);
        const float cp = RSQRT2 * (cs + sn);
        float wv[8];
        wv[0] = 0.5f - 0.5f * cs;  wv[1] = 0.5f - 0.5f * cd;
        wv[2] = 0.5f + 0.5f * sn;  wv[3] = 0.5f + 0.5f * cp;
        wv[4] = 0.5f + 0.5f * cs;  wv[5] = 0.5f + 0.5f * cd;
        wv[6] = 0.5f - 0.5f * sn;  wv[7] = 0.5f - 0.5f * cp;

        float2 a[8];
        #pragma unroll
        for (int m = 0; m < 8; ++m)
            a[m] = make_float2(xa[m] * wv[m], xv[m] * wv[m]);

        r8_store(buf[0], a, make_float2(cs, -sn), 8 * tid, 1);
    }
    __syncthreads();

    // ---- phase 1: radix-8, s=8 ----
    r8_stage<8>(buf[0], buf[1], tid);
    __syncthreads();

    // ---- phase 2: radix-8, s=64 ----
    r8_stage<64>(buf[1], buf[0], tid);
    __syncthreads();

    // ---- phase 3: radix-4, s=512 (sp = 0 for all idx -> twiddle-free) ----
    // reads X[idx+512m], writes Z[idx+512m]; XW(idx+512m) = XW(idx)+512m.
    {
        const float2* X = buf[0];
        float2*       Y = buf[1];
        #pragma unroll
        for (int u = 0; u < 2; ++u) {
            int idx = tid + 256 * u;      // [0,512)
            int wi  = XW(idx);
            float2 y0, y1, y2, y3;
            dft4(X[wi], X[wi + 512], X[wi + 1024], X[wi + 1536], y0, y1, y2, y3);
            Y[wi]        = y0;
            Y[wi + 512]  = y1;
            Y[wi + 1024] = y2;
            Y[wi + 1536] = y3;
        }
    }
    __syncthreads();

    // ---- phase 4: conjugate-symmetric unpack -> fp16 scratch ----
    // A = (Z(k) + conj(Z(-k)))/2 ; B = -i/2 (Z(k) - conj(Z(-k)))
    const float2* X5 = buf[1];
    __half2* scA = sc + ((size_t)b * FRAMES + fA) * KS;
    __half2* scB = sc + ((size_t)b * FRAMES + fB) * KS;
    #pragma unroll
    for (int j = 0; j < 5; ++j) {
        int k = tid + 256 * j;
        if (k <= 1024) {
            int m2 = (2048 - k) & 2047;
            float2 zk = X5[XW(k)];
            float2 zm = X5[XW(m2)];
            float2 A = make_float2(0.5f * (zk.x + zm.x), 0.5f * (zk.y - zm.y));
            float2 B = make_float2(0.5f * (zk.y + zm.y), 0.5f * (zm.x - zk.x));
            scA[k] = __float22half2_rn(A);
            if (hasB) scB[k] = __float22half2_rn(B);
        }
    }
}

// Tile transpose: sc[b][f][k] -> out[b][k][t] (+ conjugate mirror rows).
// XOR-swizzled tiles [c][fl][kl^fl]: 32 KB, column reads 2 lanes/bank (floor).
// sc reads vectorized 8 B/lane (2 adjacent k); out stores nontemporal.
__global__ __launch_bounds__(256, 5) void transpose_out(
    const __half2* __restrict__ sc, float* __restrict__ out)
{
    __shared__ float tile[2][64][64];

    const int b  = blockIdx.x;   // 16
    const int kt = blockIdx.y;   // 17 tiles of 64 covering k=0..1024
    const int ft = blockIdx.z;   // 9 chunks of 64 covering f=0..512
    const int k0 = kt * 64;
    const int f0 = ft * 64;
    const int tid = threadIdx.x;

    #pragma unroll
    for (int i = 0; i < 8; ++i) {
        int idx = tid + 256 * i;           // 2048 pair-slots = 64 f x 32 pairs
        int fl = idx >> 5, klp = (idx & 31) * 2;
        int f = f0 + fl;
        float2 v0 = make_float2(0.f, 0.f), v1 = v0;
        if (f < FRAMES) {
            // pair (k0+klp, k0+klp+1): max index 1025 < KS=1026.
            // half2-index = f*KS + k0 + klp: all even -> 8B-aligned.
            const __half2* sp = sc + ((size_t)b * FRAMES + f) * KS + (k0 + klp);
            float2 raw = *reinterpret_cast<const float2*>(sp);
            __half2 h0 = *reinterpret_cast<const __half2*>(&raw.x);
            __half2 h1 = *reinterpret_cast<const __half2*>(&raw.y);
            v0 = __half22float2(h0);
            v1 = __half22float2(h1);
        }
        tile[0][fl][(klp) ^ fl]     = v0.x;
        tile[1][fl][(klp) ^ fl]     = v0.y;
        tile[0][fl][(klp + 1) ^ fl] = v1.x;
        tile[1][fl][(klp + 1) ^ fl] = v1.y;
    }
    __syncthreads();

    const int wave = tid >> 6, lane = tid & 63;
    const int t = f0 + lane;
    const bool tok = (t < FRAMES);
    float* o0 = out + (size_t)b * ((size_t)N_FFT * FRAMES);
    float* o1 = out + OHALF + (size_t)b * ((size_t)N_FFT * FRAMES);

    for (int kl = wave; kl < 64; kl += 4) {
        int k = k0 + kl;
        if (k > 1024) continue;
        float vr = tile[0][lane][kl ^ lane];
        float vi = tile[1][lane][kl ^ lane];
        if (tok) {
            __builtin_nontemporal_store(vr, &o0[(size_t)k * FRAMES + t]);
            __builtin_nontemporal_store(vi, &o1[(size_t)k * FRAMES + t]);
            if (k >= 1 && k <= 1023) {
                __builtin_nontemporal_store(vr, &o0[(size_t)(N_FFT - k) * FRAMES + t]);
                __builtin_nontemporal_store(-vi, &o1[(size_t)(N_FFT - k) * FRAMES + t]);
            }
        }
    }
}

// ===================== fallback: naive =====================================

__global__ void dft_naive(const float* __restrict__ x,
                          const float* __restrict__ wsin,
                          const float* __restrict__ wcos,
                          float* __restrict__ out)
{
    size_t i = (size_t)blockIdx.x * 256 + threadIdx.x;
    if (i >= OHALF) return;
    int t = (int)(i % FRAMES);
    size_t r = i / FRAMES;
    int k = (int)(r % N_FFT);
    int b = (int)(r / N_FFT);
    float sr = 0.f, si = 0.f;
    int base = t * HOP - N_FFT / 2;
    for (int n = 0; n < N_FFT; ++n) {
        int j = base + n;
        j = (j < 0) ? -j : ((j >= LENGTH) ? (2 * LENGTH - 2 - j) : j);
        float xv = x[(size_t)b * LENGTH + j];
        sr += xv * wcos[(size_t)k * N_FFT + n];
        si += xv * wsin[(size_t)k * N_FFT + n];
    }
    out[i] = sr;
    out[OHALF + i] = -si;
}

// ------------------------------- launch ------------------------------------

extern "C" void kernel_launch(void* const* d_in, const int* in_sizes, int n_in,
                              void* d_out, int out_size, void* d_ws, size_t ws_size,
                              hipStream_t stream) {
    const float* x    = (const float*)d_in[0];
    const float* wsin = (const float*)d_in[1];
    const float* wcos = (const float*)d_in[2];
    float* out = (float*)d_out;

    const size_t sc_n    = (size_t)BATCH * FRAMES * KS;     // 8,421,408 half2
    const size_t need_ft = sc_n * sizeof(__half2);          // ~33.7 MB
    if (ws_size >= need_ft) {
        __half2* sc = (__half2*)d_ws;
        fft_pairs<<<dim3(PAIRS, BATCH), 256, 0, stream>>>(x, sc);
        transpose_out<<<dim3(BATCH, 17, 9), 256, 0, stream>>>(sc, out);
        return;
    }

    dft_naive<<<(int)((OHALF + 255) / 256), 256, 0, stream>>>(x, wsin, wcos, out);
}

// Round 9
// 204.498 us; speedup vs baseline: 1.1508x; 1.1508x over previous
//
#include <hip/hip_runtime.h>
#include <hip/hip_fp16.h>
#include <stdint.h>
#include <math.h>

// ---------------------------------------------------------------------------
// DFT_12223476924859: STFT via batched real-pair FFT (memory-bound).
//   out0[b,k,t] = Re X_t[k], out1[b,k,t] = Im X_t[k],  X_t = FFT(win*frame_t)
// Two real frames packed per complex 2048-pt FFT.
//
// R9 (this round): bisect the R8 regression (209.2 -> 235.3, +26us).
//   R8 bundled 3 changes; revert the two high-suspicion ones, keep one:
//   - REVERTED fft_pairs launch_bounds (256,4) -> (256,5). R5/R6 ran
//     fine under the 102-VGPR cap; raising it only cost occupancy (5->4).
//   - REVERTED nontemporal out stores -> plain stores.
//   - KEPT transpose_out 8B vectorized sc reads (coalescing unchanged,
//     half the load instructions, 8B alignment proved: KS/k0/klp even).
//   A/B read: ~209 => NT/launch_bounds were the regression; ~235 => the
//   vec read is the culprit, revert it next.
// R6: fp16 scratch (-31.9us; fills contend for HBM, bytes pay ~double).
// R5: radix-8 Stockham 8*8*8*4, 5 phases / 4 barriers; final radix-4
//   twiddle-free; 3 sincos/thread (window via cos(theta+m*pi/4) ids).
// R4: XW(w)=w^((w>>4)&15) involution swizzle (bank-floor verified), 32 KB
//   LDS ping-pong, frame-B global-load aliasing (B taps 0..5 = A 2..7).
// R3: sincos twiddles (no tables), fused load+window+stage-1.
// Harness fills (~79us, 538 MB re-poison @ ~6.9 TB/s) are outside our
// control and share HBM with our kernels.
// ---------------------------------------------------------------------------

#define N_FFT   2048
#define HOP     512
#define BATCH   16
#define LENGTH  262144
#define FRAMES  513
#define OHALF   ((size_t)BATCH * N_FFT * FRAMES)  // 16,809,984
#define KS      1026                      // per-frame half2 stride in scratch
#define PAIRS   257                       // ceil(513/2)

// XOR bank swizzle (float2 units): involution, zero memory overhead.
#define XW(w) ((w) ^ (((w) >> 4) & 15))

#define TWO_PI_OVER_N  3.0679615757712823e-3f   // 2*pi/2048
#define RSQRT2         0.70710678118654752f     // sqrt(2)/2

__device__ __forceinline__ float2 cmul(float2 a, float2 w) {
    return make_float2(a.x * w.x - a.y * w.y, a.x * w.y + a.y * w.x);
}
__device__ __forceinline__ float2 csq(float2 w) {
    return make_float2(w.x * w.x - w.y * w.y, 2.f * w.x * w.y);
}

// DFT4 with omega_4 = -i:  y1 = t1 - j t3, y3 = t1 + j t3.
__device__ __forceinline__ void dft4(float2 z0, float2 z1, float2 z2, float2 z3,
                                     float2& y0, float2& y1, float2& y2, float2& y3)
{
    float2 t0 = make_float2(z0.x + z2.x, z0.y + z2.y);
    float2 t1 = make_float2(z0.x - z2.x, z0.y - z2.y);
    float2 t2 = make_float2(z1.x + z3.x, z1.y + z3.y);
    float2 t3 = make_float2(z1.x - z3.x, z1.y - z3.y);
    y0 = make_float2(t0.x + t2.x, t0.y + t2.y);
    y1 = make_float2(t1.x + t3.y, t1.y - t3.x);
    y2 = make_float2(t0.x - t2.x, t0.y - t2.y);
    y3 = make_float2(t1.x - t3.y, t1.y + t3.x);
}

// Radix-8 DIF butterfly on a[0..7], then Y[XW(obase + m*s)] = y_m * w1^m.
// y_{2m} = DFT4(a_n + a_{n+4})_m ; y_{2m+1} = DFT4((a_n - a_{n+4}) w8^n)_m.
__device__ __forceinline__ void r8_store(float2* __restrict__ Y, const float2 a[8],
                                         float2 w1, int obase, int s)
{
    float2 u0 = make_float2(a[0].x + a[4].x, a[0].y + a[4].y);
    float2 u1 = make_float2(a[1].x + a[5].x, a[1].y + a[5].y);
    float2 u2 = make_float2(a[2].x + a[6].x, a[2].y + a[6].y);
    float2 u3 = make_float2(a[3].x + a[7].x, a[3].y + a[7].y);
    float2 v0 = make_float2(a[0].x - a[4].x, a[0].y - a[4].y);
    float2 v1 = make_float2(a[1].x - a[5].x, a[1].y - a[5].y);
    float2 v2 = make_float2(a[2].x - a[6].x, a[2].y - a[6].y);
    float2 v3 = make_float2(a[3].x - a[7].x, a[3].y - a[7].y);
    // v_n *= w8^n: w8 = (c,-c), w8^2 = -i, w8^3 = (-c,-c), c = sqrt(2)/2
    v1 = make_float2(RSQRT2 * (v1.x + v1.y), RSQRT2 * (v1.y - v1.x));
    v2 = make_float2(v2.y, -v2.x);
    v3 = make_float2(RSQRT2 * (v3.y - v3.x), -RSQRT2 * (v3.x + v3.y));

    float2 E0, E1, E2, E3, O0, O1, O2, O3;
    dft4(u0, u1, u2, u3, E0, E1, E2, E3);
    dft4(v0, v1, v2, v3, O0, O1, O2, O3);

    float2 w2 = csq(w1);
    float2 w3 = cmul(w1, w2);
    float2 w4 = csq(w2);
    float2 w5 = cmul(w2, w3);
    float2 w6 = csq(w3);
    float2 w7 = cmul(w3, w4);

    Y[XW(obase)]         = E0;
    Y[XW(obase + s)]     = cmul(O0, w1);
    Y[XW(obase + 2 * s)] = cmul(E1, w2);
    Y[XW(obase + 3 * s)] = cmul(O1, w3);
    Y[XW(obase + 4 * s)] = cmul(E2, w4);
    Y[XW(obase + 5 * s)] = cmul(O2, w5);
    Y[XW(obase + 6 * s)] = cmul(E3, w6);
    Y[XW(obase + 7 * s)] = cmul(O3, w7);
}

// Middle radix-8 stage (S = 8 or 64): read, twiddle from 1 sincos, write.
template<int S>
__device__ __forceinline__ void r8_stage(const float2* __restrict__ X,
                                         float2* __restrict__ Y, int idx)
{
    float2 a[8];
    const int wi = XW(idx);               // XW(idx+256m) = XW(idx)+256m
    #pragma unroll
    for (int m = 0; m < 8; ++m) a[m] = X[wi + 256 * m];
    const int sp = idx & ~(S - 1);
    float sn, cs;
    __sincosf((float)sp * TWO_PI_OVER_N, &sn, &cs);
    r8_store(Y, a, make_float2(cs, -sn), idx + 7 * sp, S);
}

// ============================ FFT path =====================================

// One block = one pair of frames (2p, 2p+1) of one batch.
// z = wxA + i*wxB; radix-8 Stockham (8*8*8*4), XOR-swizzled LDS ping-pong.
__global__ __launch_bounds__(256, 5) void fft_pairs(
    const float* __restrict__ x, __half2* __restrict__ sc)
{
    __shared__ float2 buf[2][2048];   // exactly 32 KB ping-pong

    const int tid = threadIdx.x;      // = butterfly idx for radix-8 stages
    const int p   = blockIdx.x;       // pair index 0..256
    const int b   = blockIdx.y;
    const int fA  = 2 * p;
    const int fB  = 2 * p + 1;
    const bool hasB = (fB < FRAMES);
    const float* xb = x + (size_t)b * LENGTH;
    const bool interior = (p >= 1 && p <= 254);

    // ---- phase 0: load + window + radix-8 stage s=1 (fused) ----
    // tap n = tid + 256m; win(n) = 0.5 - 0.5 cos(theta + m*pi/4),
    // theta = 2*pi*tid/2048; stage twiddle w1 = (cos theta, -sin theta).
    {
        const int baseA = fA * HOP - (N_FFT / 2);
        float xa[8], xv[8];
        if (interior) {
            #pragma unroll
            for (int m = 0; m < 8; ++m) xa[m] = xb[baseA + tid + 256 * m];
            #pragma unroll
            for (int m = 0; m < 6; ++m) xv[m] = xa[m + 2];   // baseB = baseA+512
            xv[6] = xb[baseA + 512 + tid + 256 * 6];
            xv[7] = xb[baseA + 512 + tid + 256 * 7];
        } else {
            const int baseB = baseA + 512;
            #pragma unroll
            for (int m = 0; m < 8; ++m) {
                int ja = baseA + tid + 256 * m;
                ja = (ja < 0) ? -ja : ((ja >= LENGTH) ? 2 * LENGTH - 2 - ja : ja);
                xa[m] = xb[ja];
                float vb = 0.f;
                if (hasB) {
                    int jb = baseB + tid + 256 * m;
                    jb = (jb < 0) ? -jb : ((jb >= LENGTH) ? 2 * LENGTH - 2 - jb : jb);
                    vb = xb[jb];
                }
                xv[m] = vb;
            }
        }
        float sn, cs;
        __sincosf((float)tid * TWO_PI_OVER_N, &sn, &cs);
        const float cd = RSQRT2 * (cs - sn);
        const float cp = RSQRT2 * (cs + sn);
        float wv[8];
        wv[0] = 0.5f - 0.5f * cs;  wv[1] = 0.5f - 0.5f * cd;
        wv[2] = 0.5f + 0.5f * sn;  wv[3] = 0.5f + 0.5f * cp;
        wv[4] = 0.5f + 0.5f * cs;  wv[5] = 0.5f + 0.5f * cd;
        wv[6] = 0.5f - 0.5f * sn;  wv[7] = 0.5f - 0.5f * cp;

        float2 a[8];
        #pragma unroll
        for (int m = 0; m < 8; ++m)
            a[m] = make_float2(xa[m] * wv[m], xv[m] * wv[m]);

        r8_store(buf[0], a, make_float2(cs, -sn), 8 * tid, 1);
    }
    __syncthreads();

    // ---- phase 1: radix-8, s=8 ----
    r8_stage<8>(buf[0], buf[1], tid);
    __syncthreads();

    // ---- phase 2: radix-8, s=64 ----
    r8_stage<64>(buf[1], buf[0], tid);
    __syncthreads();

    // ---- phase 3: radix-4, s=512 (sp = 0 for all idx -> twiddle-free) ----
    // reads X[idx+512m], writes Z[idx+512m]; XW(idx+512m) = XW(idx)+512m.
    {
        const float2* X = buf[0];
        float2*       Y = buf[1];
        #pragma unroll
        for (int u = 0; u < 2; ++u) {
            int idx = tid + 256 * u;      // [0,512)
            int wi  = XW(idx);
            float2 y0, y1, y2, y3;
            dft4(X[wi], X[wi + 512], X[wi + 1024], X[wi + 1536], y0, y1, y2, y3);
            Y[wi]        = y0;
            Y[wi + 512]  = y1;
            Y[wi + 1024] = y2;
            Y[wi + 1536] = y3;
        }
    }
    __syncthreads();

    // ---- phase 4: conjugate-symmetric unpack -> fp16 scratch ----
    // A = (Z(k) + conj(Z(-k)))/2 ; B = -i/2 (Z(k) - conj(Z(-k)))
    const float2* X5 = buf[1];
    __half2* scA = sc + ((size_t)b * FRAMES + fA) * KS;
    __half2* scB = sc + ((size_t)b * FRAMES + fB) * KS;
    #pragma unroll
    for (int j = 0; j < 5; ++j) {
        int k = tid + 256 * j;
        if (k <= 1024) {
            int m2 = (2048 - k) & 2047;
            float2 zk = X5[XW(k)];
            float2 zm = X5[XW(m2)];
            float2 A = make_float2(0.5f * (zk.x + zm.x), 0.5f * (zk.y - zm.y));
            float2 B = make_float2(0.5f * (zk.y + zm.y), 0.5f * (zm.x - zk.x));
            scA[k] = __float22half2_rn(A);
            if (hasB) scB[k] = __float22half2_rn(B);
        }
    }
}

// Tile transpose: sc[b][f][k] -> out[b][k][t] (+ conjugate mirror rows).
// XOR-swizzled tiles [c][fl][kl^fl]: 32 KB, column reads 2 lanes/bank (floor).
// sc reads vectorized 8 B/lane (2 adjacent k); plain out stores.
__global__ __launch_bounds__(256, 5) void transpose_out(
    const __half2* __restrict__ sc, float* __restrict__ out)
{
    __shared__ float tile[2][64][64];

    const int b  = blockIdx.x;   // 16
    const int kt = blockIdx.y;   // 17 tiles of 64 covering k=0..1024
    const int ft = blockIdx.z;   // 9 chunks of 64 covering f=0..512
    const int k0 = kt * 64;
    const int f0 = ft * 64;
    const int tid = threadIdx.x;

    #pragma unroll
    for (int i = 0; i < 8; ++i) {
        int idx = tid + 256 * i;           // 2048 pair-slots = 64 f x 32 pairs
        int fl = idx >> 5, klp = (idx & 31) * 2;
        int f = f0 + fl;
        float2 v0 = make_float2(0.f, 0.f), v1 = v0;
        if (f < FRAMES) {
            // pair (k0+klp, k0+klp+1): max index 1025 < KS=1026.
            // half2-index = f*KS + k0 + klp: all even -> 8B-aligned.
            const __half2* sp = sc + ((size_t)b * FRAMES + f) * KS + (k0 + klp);
            float2 raw = *reinterpret_cast<const float2*>(sp);
            __half2 h0 = *reinterpret_cast<const __half2*>(&raw.x);
            __half2 h1 = *reinterpret_cast<const __half2*>(&raw.y);
            v0 = __half22float2(h0);
            v1 = __half22float2(h1);
        }
        tile[0][fl][(klp) ^ fl]     = v0.x;
        tile[1][fl][(klp) ^ fl]     = v0.y;
        tile[0][fl][(klp + 1) ^ fl] = v1.x;
        tile[1][fl][(klp + 1) ^ fl] = v1.y;
    }
    __syncthreads();

    const int wave = tid >> 6, lane = tid & 63;
    const int t = f0 + lane;
    const bool tok = (t < FRAMES);
    float* o0 = out + (size_t)b * ((size_t)N_FFT * FRAMES);
    float* o1 = out + OHALF + (size_t)b * ((size_t)N_FFT * FRAMES);

    for (int kl = wave; kl < 64; kl += 4) {
        int k = k0 + kl;
        if (k > 1024) continue;
        float vr = tile[0][lane][kl ^ lane];
        float vi = tile[1][lane][kl ^ lane];
        if (tok) {
            o0[(size_t)k * FRAMES + t] = vr;
            o1[(size_t)k * FRAMES + t] = vi;
            if (k >= 1 && k <= 1023) {
                o0[(size_t)(N_FFT - k) * FRAMES + t] = vr;
                o1[(size_t)(N_FFT - k) * FRAMES + t] = -vi;
            }
        }
    }
}

// ===================== fallback: naive =====================================

__global__ void dft_naive(const float* __restrict__ x,
                          const float* __restrict__ wsin,
                          const float* __restrict__ wcos,
                          float* __restrict__ out)
{
    size_t i = (size_t)blockIdx.x * 256 + threadIdx.x;
    if (i >= OHALF) return;
    int t = (int)(i % FRAMES);
    size_t r = i / FRAMES;
    int k = (int)(r % N_FFT);
    int b = (int)(r / N_FFT);
    float sr = 0.f, si = 0.f;
    int base = t * HOP - N_FFT / 2;
    for (int n = 0; n < N_FFT; ++n) {
        int j = base + n;
        j = (j < 0) ? -j : ((j >= LENGTH) ? (2 * LENGTH - 2 - j) : j);
        float xv = x[(size_t)b * LENGTH + j];
        sr += xv * wcos[(size_t)k * N_FFT + n];
        si += xv * wsin[(size_t)k * N_FFT + n];
    }
    out[i] = sr;
    out[OHALF + i] = -si;
}

// ------------------------------- launch ------------------------------------

extern "C" void kernel_launch(void* const* d_in, const int* in_sizes, int n_in,
                              void* d_out, int out_size, void* d_ws, size_t ws_size,
                              hipStream_t stream) {
    const float* x    = (const float*)d_in[0];
    const float* wsin = (const float*)d_in[1];
    const float* wcos = (const float*)d_in[2];
    float* out = (float*)d_out;

    const size_t sc_n    = (size_t)BATCH * FRAMES * KS;     // 8,421,408 half2
    const size_t need_ft = sc_n * sizeof(__half2);          // ~33.7 MB
    if (ws_size >= need_ft) {
        __half2* sc = (__half2*)d_ws;
        fft_pairs<<<dim3(PAIRS, BATCH), 256, 0, stream>>>(x, sc);
        transpose_out<<<dim3(BATCH, 17, 9), 256, 0, stream>>>(sc, out);
        return;
    }

    dft_naive<<<(int)((OHALF + 255) / 256), 256, 0, stream>>>(x, wsin, wcos, out);
}